// Round 9
// baseline (1428.684 us; speedup 1.0000x reference)
//
#include <hip/hip_runtime.h>
#include <hip/hip_bf16.h>
#include <stdint.h>

// Problem constants
constexpr int NB   = 128;   // batch
constexpr int NC   = 2;     // grid channels
constexpr int NH   = 150;   // hidden
constexpr int NA   = 8;     // actions
constexpr int KIT  = 30;    // VI iterations
constexpr int GN   = 49;    // grid spatial
constexpr int HPN  = 51;    // padded spatial (49+2)
constexpr int NP   = HPN * HPN;  // 2601 positions
constexpr int RTC  = 73;    // 1 reward + 72 trans channels
constexpr int CIP  = 160;   // padded channel count (multiple of 32)

typedef short v8bf __attribute__((ext_vector_type(8)));
typedef float v4f  __attribute__((ext_vector_type(4)));

__device__ __forceinline__ float bf_lo(uint32_t u){ return __uint_as_float(u << 16); }
__device__ __forceinline__ float bf_hi(uint32_t u){ return __uint_as_float(u & 0xffff0000u); }

__device__ __forceinline__ uint16_t f2bf(float f) {
    uint32_t u = __float_as_uint(f);
    uint32_t lsb = (u >> 16) & 1u;
    u += 0x7fffu + lsb;
    return (uint16_t)(u >> 16);
}

// Load element i of a buffer whose dtype is bf16 (isbf=1) or f32 (isbf=0), as float.
__device__ __forceinline__ float ld_f(const void* p, size_t i, int isbf) {
    if (isbf) {
        uint32_t b = ((const uint16_t*)p)[i];
        return __uint_as_float(b << 16);
    }
    return ((const float*)p)[i];
}
__device__ __forceinline__ uint16_t ld_bf_bits(const void* p, size_t i, int isbf) {
    if (isbf) return ((const uint16_t*)p)[i];
    return f2bf(((const float*)p)[i]);
}

// ---------------- dtype sniffer ---------------------------------------------------------
__global__ void detect_kernel(const uint16_t* __restrict__ w, int* __restrict__ flag)
{
    int i = threadIdx.x;  // 0..63
    uint32_t bits = w[2 * i];
    float f = __uint_as_float(bits << 16);
    float a = fabsf(f);
    bool ok = (a >= 1e-10f && a <= 1e5f);
    unsigned long long m = __ballot(ok);
    if (i == 0) flag[0] = (__popcll(m) >= 48) ? 1 : 0;
}

// ---------------- prep: layout transforms -----------------------------------------------
// grid_cl [b][49][49][2] bf16 ; wT1 f32 [(k*2+ci)*150+co] ; bias1 f32[150]
// w2t bf16 [tap][kc5][160 co][32 ci]  (zero padded)  ; bias2 f32[160]
// wrt bf16 [tap][kc5][80 co][32 ci]   (co0 = reward, co1..72 = trans, zero padded)
__global__ void prep_kernel(const void* __restrict__ g,
                            const void* __restrict__ w1,
                            const void* __restrict__ b1,
                            const void* __restrict__ w2,
                            const void* __restrict__ b2,
                            const void* __restrict__ rw,
                            const void* __restrict__ tw,
                            const void* __restrict__ a1w,
                            const void* __restrict__ a1b,
                            const void* __restrict__ a2w,
                            const void* __restrict__ a2b,
                            const int* __restrict__ flag,
                            uint16_t* __restrict__ grid_cl,
                            float* __restrict__ wT1, float* __restrict__ bias1,
                            uint16_t* __restrict__ w2t, float* __restrict__ bias2,
                            uint16_t* __restrict__ wrt,
                            float* __restrict__ wA1, float* __restrict__ bA1,
                            float* __restrict__ wA2, float* __restrict__ bA2)
{
    constexpr int N_GRID = NB * GN * GN * NC;        // 614656
    constexpr int N_WT1  = 9 * NC * NH;              // 2700
    constexpr int N_B1   = NH;
    constexpr int N_W2T  = 9 * 5 * CIP * 32;         // 230400
    constexpr int N_B2   = CIP;
    constexpr int N_WRT  = 9 * 5 * 80 * 32;          // 115200
    constexpr int N_A1W  = NH * NA;
    constexpr int N_A1B  = NH;
    constexpr int N_A2W  = NA * NH;
    constexpr int N_A2B  = NA;

    int isbf = flag[0];
    int i = blockIdx.x * blockDim.x + threadIdx.x;
    if (i < N_GRID) {
        int c = i & 1; int s = (i >> 1) % (GN*GN); int b = i / (GN*GN*2);
        grid_cl[i] = ld_bf_bits(g, (size_t)(b*NC + c)*(GN*GN) + s, isbf);
        return;
    }
    i -= N_GRID;
    if (i < N_WT1) {
        int co = i % NH; int r = i / NH; int ci = r & 1; int k = r >> 1;
        wT1[i] = ld_f(w1, (size_t)co*(NC*9) + ci*9 + k, isbf);
        return;
    }
    i -= N_WT1;
    if (i < N_B1) { bias1[i] = ld_f(b1, i, isbf); return; }
    i -= N_B1;
    if (i < N_W2T) {
        int c  = i % 32;
        int co = (i / 32) % CIP;
        int kc = (i / (32*CIP)) % 5;
        int tap = i / (32*CIP*5);
        int ci = kc*32 + c;
        uint16_t v = 0;
        if (co < NH && ci < NH)
            v = f2bf(ld_f(w2, ((size_t)co*NH + ci)*9 + tap, isbf));
        w2t[i] = v;
        return;
    }
    i -= N_W2T;
    if (i < N_B2) { bias2[i] = (i < NH) ? ld_f(b2, i, isbf) : 0.f; return; }
    i -= N_B2;
    if (i < N_WRT) {
        int c  = i % 32;
        int co = (i / 32) % 80;
        int kc = (i / 2560) % 5;
        int tap = i / 12800;
        int ci = kc*32 + c;
        uint16_t v = 0;
        if (ci < NH) {
            if (co == 0)        v = f2bf(ld_f(rw, (size_t)ci*9 + tap, isbf));
            else if (co <= 72)  v = f2bf(ld_f(tw, ((size_t)(co-1)*NH + ci)*9 + tap, isbf));
        }
        wrt[i] = v;
        return;
    }
    i -= N_WRT;
    if (i < N_A1W) { wA1[i] = ld_f(a1w, i, isbf); return; }
    i -= N_A1W;
    if (i < N_A1B) { bA1[i] = ld_f(a1b, i, isbf); return; }
    i -= N_A1B;
    if (i < N_A2W) { wA2[i] = ld_f(a2w, i, isbf); return; }
    i -= N_A2W;
    if (i < N_A2B) { bA2[i] = ld_f(a2b, i, isbf); return; }
}

// ---------------- conv1: 2->150 VALU, writes 160-padded bf16 ----------------------------
__global__ __launch_bounds__(192)
void conv1_cl(const uint16_t* __restrict__ in,   // [b][49][49][2] bf16
              const float* __restrict__ wT,      // [(k*2+ci)*150+co]
              const float* __restrict__ bias,    // f32 [150]
              uint16_t* __restrict__ out)        // [b][49][49][160] bf16
{
    constexpr int H = GN, XG = 13;
    int bid = blockIdx.x;
    int xg = bid % XG;
    int y  = (bid / XG) % H;
    int b  = bid / (XG * H);
    int x0 = xg * 4;
    int co = threadIdx.x;

    if (co >= NH) {
        if (co < CIP) {
            #pragma unroll
            for (int xi = 0; xi < 4; ++xi) {
                int x = x0 + xi;
                if (x < H) out[((size_t)(b*H + y)*H + x)*CIP + co] = 0;
            }
        }
        return;
    }

    float bv = bias[co];
    float acc[4] = {bv, bv, bv, bv};

    for (int ky = 0; ky < 3; ++ky) {
        int yy = y + ky - 1;
        if (yy < 0 || yy >= H) continue;
        const uint16_t* rowp = in + (size_t)(b * H + yy) * H * NC;
        #pragma unroll
        for (int kx = 0; kx < 3; ++kx) {
            const float* wp = wT + ((ky*3 + kx) * NC) * NH + co;
            float w0 = wp[0];
            float w1 = wp[NH];
            #pragma unroll
            for (int xi = 0; xi < 4; ++xi) {
                int xx = x0 + xi + kx - 1;
                if (xx < 0 || xx >= H) continue;
                uint32_t u = *(const uint32_t*)(rowp + (size_t)xx * NC);
                acc[xi] += bf_lo(u)*w0 + bf_hi(u)*w1;
            }
        }
    }
    #pragma unroll
    for (int xi = 0; xi < 4; ++xi) {
        int x = x0 + xi;
        if (x < H) out[((size_t)(b*H + y)*H + x)*CIP + co] = f2bf(fmaxf(acc[xi], 0.f));
    }
}

// ---------------- MFMA implicit-GEMM 3x3 conv, v7 ---------------------------------------
// Round-8 geometry (128 thr, 4 rows/wave, 8-row tile, halo 10x18 staged once) with a
// DEEP register pipeline on B: rolling 4-stage buffer of per-lane global loads (the
// vmcnt(N>0) pattern), full unroll of the 45-stage K-loop so buffer indices and LDS
// offsets are compile-time constants. A double-buffered from LDS. No K-loop barriers.
template<int CO_T, int CO_S, int PAD, int OH, bool RELU, bool OBF>
__global__ __launch_bounds__(128, 1)
void conv_mfma(const uint16_t* __restrict__ in,   // [b][49][49][160] bf16
               const uint16_t* __restrict__ wt,   // [tap][kc][CO_T][32] bf16
               const float* __restrict__ bias,
               void* __restrict__ outv)
{
    constexpr int H = GN;
    constexpr int NSUB = CO_S / 16;        // 5
    constexpr int CS = CO_T / CO_S;        // 2 (conv2) or 1 (RT)
    constexpr int AS = 168;                // halo ci stride in shorts (160 + 8 pad)
    constexpr int NST = 45;                // 9 taps x 5 kc
    constexpr int RG = (OH + 7) / 8;       // 8-row tiles
    constexpr int PF = 4;                  // B prefetch depth (stages in flight)
    static_assert(NSUB * 16 == CO_S && CS * CO_S == CO_T, "");

    __shared__ __align__(16) uint16_t shA[10 * 18 * AS];   // 60480 B

    int bid = blockIdx.x;
    int cs = 0;
    if (CS > 1) { cs = bid % CS; bid /= CS; }
    int xg = bid & 3; bid >>= 2;
    int rg = bid % RG;
    int b  = bid / RG;
    int y0 = rg * 8, x0 = xg * 16;
    int co0 = cs * CO_S;
    int t = threadIdx.x;
    int w = t >> 6, l = t & 63;
    int lo16 = l & 15, q4 = l >> 4;

    // ---- stage halo once: 10 rows x 18 cols x 20 ci8-chunks = 3600 16B chunks
    for (int q = t; q < 10*18*20; q += 128) {
        int ci8 = q % 20;
        int c   = (q / 20) % 18;
        int r   = q / 360;
        int yy = y0 + r - PAD, xx = x0 + c - PAD;
        uint4 v = make_uint4(0u, 0u, 0u, 0u);
        if (yy >= 0 && yy < H && xx >= 0 && xx < H)
            v = *(const uint4*)(in + ((size_t)(b*H + yy)*H + xx)*CIP + ci8*8);
        *(uint4*)(&shA[(r*18 + c)*AS + ci8*8]) = v;
    }
    __syncthreads();

    // ---- per-lane B base: fragment (s,n) = wbase + s*CO_T*32 + n*512
    const uint16_t* wbase = wt + (size_t)co0*32 + lo16*32 + q4*8;

    v4f acc[4][NSUB];
    #pragma unroll
    for (int si = 0; si < 4; ++si)
        #pragma unroll
        for (int n = 0; n < NSUB; ++n)
            acc[si][n] = (v4f){0.f, 0.f, 0.f, 0.f};

    auto loadB = [&](int s, v8bf* bf) {
        const uint16_t* p = wbase + (size_t)s * (CO_T*32);
        #pragma unroll
        for (int n = 0; n < NSUB; ++n)
            bf[n] = *(const v8bf*)(p + n*512);
    };
    auto loadA = [&](int s, v8bf* af) {
        int tap = s / 5, kc = s % 5;
        int ky = tap / 3, kx = tap % 3;
        const uint16_t* base = &shA[((4*w + ky)*18 + lo16 + kx)*AS + kc*32 + q4*8];
        #pragma unroll
        for (int si = 0; si < 4; ++si)
            af[si] = *(const v8bf*)(base + si*(18*AS));
    };
    auto compute = [&](v8bf* af, v8bf* bf) {
        #pragma unroll
        for (int n = 0; n < NSUB; ++n) {
            #pragma unroll
            for (int si = 0; si < 4; ++si)
                acc[si][n] = __builtin_amdgcn_mfma_f32_16x16x32_bf16(af[si], bf[n], acc[si][n], 0, 0, 0);
        }
    };

    // ---- deep software pipeline: B loaded PF-1 stages ahead, A one stage ahead
    v8bf bfb[PF][NSUB];
    v8bf afb[2][4];
    #pragma unroll
    for (int s = 0; s < PF - 1; ++s) loadB(s, bfb[s]);
    loadA(0, afb[0]);

    #pragma unroll
    for (int s = 0; s < NST; ++s) {
        if (s + PF - 1 < NST) loadB(s + PF - 1, bfb[(s + PF - 1) % PF]);
        if (s + 1 < NST)      loadA(s + 1, afb[(s + 1) & 1]);
        compute(afb[s & 1], bfb[s % PF]);
    }

    // ---- epilogue: C/D layout: co = co0 + n*16 + (l&15), x = x0 + q4*4 + reg
    #pragma unroll
    for (int si = 0; si < 4; ++si) {
        int y = y0 + 4*w + si;
        if (y >= OH) continue;
        #pragma unroll
        for (int n = 0; n < NSUB; ++n) {
            int co = co0 + n*16 + lo16;
            float bv = bias ? bias[co] : 0.f;
            #pragma unroll
            for (int r = 0; r < 4; ++r) {
                int x = x0 + q4*4 + r;
                if (x >= OH) continue;
                float v = acc[si][n][r] + bv;
                if (RELU) v = fmaxf(v, 0.f);
                if (OBF) {
                    ((uint16_t*)outv)[((size_t)(b*OH + y)*OH + x)*CIP + co] = f2bf(v);
                } else {
                    if (co < RTC)
                        ((float*)outv)[((size_t)(b*OH + y)*OH + x)*RTC + co] = v;
                }
            }
        }
    }
}

// ---------------- softmax + u16 fixed-point pack ----------------------------------------
__global__ void softmax_pack_kernel(const float* __restrict__ rt,
                                    uint32_t* __restrict__ sTu,
                                    float* __restrict__ rewb)
{
    int idx = blockIdx.x * blockDim.x + threadIdx.x;
    constexpr int TOT = NB * NP;
    if (idx >= TOT) return;
    const float* tp = rt + (size_t)idx * RTC;
    rewb[idx] = tp[0];
    uint32_t words[36];
    #pragma unroll
    for (int a = 0; a < NA; ++a) {
        const float* s = tp + 1 + a * 9;
        float v[9];
        float m = -1e30f;
        #pragma unroll
        for (int k = 0; k < 9; ++k) { v[k] = s[k]; m = fmaxf(m, v[k]); }
        float sum = 0.f;
        #pragma unroll
        for (int k = 0; k < 9; ++k) { v[k] = expf(v[k] - m); sum += v[k]; }
        float sc = 65535.f / sum;
        #pragma unroll
        for (int k = 0; k < 9; ++k) {
            int gi = a * 9 + k;
            uint32_t u = (uint32_t)__float2uint_rn(v[k] * sc);
            if (gi & 1) words[gi >> 1] |= (u << 16);
            else        words[gi >> 1] = u;
        }
    }
    uint32_t* op = sTu + (size_t)idx * 36;
    #pragma unroll
    for (int j = 0; j < 9; ++j)
        *(uint4*)(op + 4*j) = make_uint4(words[4*j], words[4*j+1], words[4*j+2], words[4*j+3]);
}

// ---------------- VI inner: one action-pair (9 dwords = 18 u16 taps) --------------------
__device__ __forceinline__ void vi_pair(const uint32_t* d, const float* pat,
                                        float r, float& qE, float& qO)
{
    float qe = 0.f, qo = 0.f;
    qe = fmaf((float)(d[0] & 0xffffu), pat[0], qe);
    qe = fmaf((float)(d[0] >> 16),     pat[1], qe);
    qe = fmaf((float)(d[1] & 0xffffu), pat[2], qe);
    qe = fmaf((float)(d[1] >> 16),     pat[3], qe);
    qe = fmaf((float)(d[2] & 0xffffu), pat[4], qe);
    qe = fmaf((float)(d[2] >> 16),     pat[5], qe);
    qe = fmaf((float)(d[3] & 0xffffu), pat[6], qe);
    qe = fmaf((float)(d[3] >> 16),     pat[7], qe);
    qe = fmaf((float)(d[4] & 0xffffu), pat[8], qe);
    qo = fmaf((float)(d[4] >> 16),     pat[0], qo);
    qo = fmaf((float)(d[5] & 0xffffu), pat[1], qo);
    qo = fmaf((float)(d[5] >> 16),     pat[2], qo);
    qo = fmaf((float)(d[6] & 0xffffu), pat[3], qo);
    qo = fmaf((float)(d[6] >> 16),     pat[4], qo);
    qo = fmaf((float)(d[7] & 0xffffu), pat[5], qo);
    qo = fmaf((float)(d[7] >> 16),     pat[6], qo);
    qo = fmaf((float)(d[8] & 0xffffu), pat[7], qo);
    qo = fmaf((float)(d[8] >> 16),     pat[8], qo);
    constexpr float inv = 1.f / 65535.f;
    qE = fmaf(qe, inv, r);
    qO = fmaf(qo, inv, r);
}

// ---------------- persistent value iteration: sT register-resident ----------------------
__global__ __launch_bounds__(1024, 1)
void vi_kernel(const uint32_t* __restrict__ sTu, const float* __restrict__ rewb,
               float* __restrict__ qout)
{
    __shared__ float vb[2][53*53];
    __shared__ float rew[NP];
    int b = blockIdx.x, t = threadIdx.x;
    for (int i = t; i < 53*53; i += 1024) { vb[0][i] = 0.f; vb[1][i] = 0.f; }
    const uint32_t* sb = sTu + (size_t)b * NP * 36;
    for (int i = t; i < NP; i += 1024) rew[i] = rewb[(size_t)b * NP + i];

    int p0 = t, p1 = t + 1024, p2 = t + 2048;
    uint32_t s0[36], s1[36];
    {
        const uint4* a0 = (const uint4*)(sb + (size_t)p0 * 36);
        const uint4* a1 = (const uint4*)(sb + (size_t)p1 * 36);
        #pragma unroll
        for (int j = 0; j < 9; ++j) {
            uint4 v = a0[j];
            s0[4*j+0]=v.x; s0[4*j+1]=v.y; s0[4*j+2]=v.z; s0[4*j+3]=v.w;
            uint4 u = a1[j];
            s1[4*j+0]=u.x; s1[4*j+1]=u.y; s1[4*j+2]=u.z; s1[4*j+3]=u.w;
        }
    }
    __syncthreads();

    float* qb = qout + (size_t)b * NP * NA;
    int cur = 0;
    for (int it = 0; it < KIT; ++it) {
        bool last = (it == KIT - 1);
        const float* vc = vb[cur];
        float* vn = vb[cur ^ 1];
        {
            int y = p0 / HPN, x = p0 % HPN;
            float pat[9];
            #pragma unroll
            for (int dy = 0; dy < 3; ++dy)
                #pragma unroll
                for (int dx = 0; dx < 3; ++dx)
                    pat[dy*3+dx] = vc[(y+dy)*53 + x+dx];
            float r = rew[p0];
            float best = -3.4e38f;
            #pragma unroll
            for (int ap = 0; ap < 4; ++ap) {
                float qE, qO;
                vi_pair(s0 + ap*9, pat, r, qE, qO);
                best = fmaxf(best, fmaxf(qE, qO));
                if (last) {
                    qb[(size_t)p0*NA + 2*ap]     = qE;
                    qb[(size_t)p0*NA + 2*ap + 1] = qO;
                }
            }
            vn[(y+1)*53 + x+1] = best;
        }
        {
            int y = p1 / HPN, x = p1 % HPN;
            float pat[9];
            #pragma unroll
            for (int dy = 0; dy < 3; ++dy)
                #pragma unroll
                for (int dx = 0; dx < 3; ++dx)
                    pat[dy*3+dx] = vc[(y+dy)*53 + x+dx];
            float r = rew[p1];
            float best = -3.4e38f;
            #pragma unroll
            for (int ap = 0; ap < 4; ++ap) {
                float qE, qO;
                vi_pair(s1 + ap*9, pat, r, qE, qO);
                best = fmaxf(best, fmaxf(qE, qO));
                if (last) {
                    qb[(size_t)p1*NA + 2*ap]     = qE;
                    qb[(size_t)p1*NA + 2*ap + 1] = qO;
                }
            }
            vn[(y+1)*53 + x+1] = best;
        }
        if (t < NP - 2048) {
            int y = p2 / HPN, x = p2 % HPN;
            float pat[9];
            #pragma unroll
            for (int dy = 0; dy < 3; ++dy)
                #pragma unroll
                for (int dx = 0; dx < 3; ++dx)
                    pat[dy*3+dx] = vc[(y+dy)*53 + x+dx];
            float r = rew[p2];
            float best = -3.4e38f;
            const uint32_t* gp = sb + (size_t)p2 * 36;
            #pragma unroll
            for (int ap = 0; ap < 4; ++ap) {
                uint32_t d[9];
                #pragma unroll
                for (int j = 0; j < 9; ++j) d[j] = gp[ap*9 + j];
                float qE, qO;
                vi_pair(d, pat, r, qE, qO);
                best = fmaxf(best, fmaxf(qE, qO));
                if (last) {
                    qb[(size_t)p2*NA + 2*ap]     = qE;
                    qb[(size_t)p2*NA + 2*ap + 1] = qO;
                }
            }
            vn[(y+1)*53 + x+1] = best;
        }
        __syncthreads();
        cur ^= 1;
    }
}

// ---------------- fused MLP head: q(8) -> relu(150) -> logits(8) -------------------------
__global__ void head_kernel(const float* __restrict__ q,
                            const float* __restrict__ wA1,
                            const float* __restrict__ bA1,
                            const float* __restrict__ wA2,
                            const float* __restrict__ bA2,
                            const int* __restrict__ flag,
                            void* __restrict__ out)
{
    __shared__ float w1[NH*NA], sb1[NH], w2[NA*NH], sb2[NA];
    int t = threadIdx.x;
    for (int i = t; i < NH*NA; i += 256) w1[i] = wA1[i];
    for (int i = t; i < NH;    i += 256) sb1[i] = bA1[i];
    for (int i = t; i < NA*NH; i += 256) w2[i] = wA2[i];
    if (t < NA) sb2[t] = bA2[t];
    __syncthreads();

    int isbf = flag[0];
    int idx = blockIdx.x * 256 + t;
    constexpr int TOT = NB * GN * GN;
    if (idx >= TOT) return;
    int x = idx % GN, y = (idx / GN) % GN, b = idx / (GN*GN);
    const float* qp = q + ((size_t)(b*HPN + y)*HPN + x) * NA;
    float qv[NA];
    #pragma unroll
    for (int a = 0; a < NA; ++a) qv[a] = qp[a];
    float lg[NA];
    #pragma unroll
    for (int a = 0; a < NA; ++a) lg[a] = sb2[a];
    for (int c = 0; c < NH; ++c) {
        float m = sb1[c];
        #pragma unroll
        for (int a = 0; a < NA; ++a) m += qv[a] * w1[c*NA + a];
        m = fmaxf(m, 0.f);
        #pragma unroll
        for (int a = 0; a < NA; ++a) lg[a] += m * w2[a*NH + c];
    }
    #pragma unroll
    for (int a = 0; a < NA; ++a) {
        size_t oi = ((size_t)(b*NA + a)*GN + y)*GN + x;
        float r = lg[a];
        if (isbf) ((uint16_t*)out)[oi] = f2bf(r);
        else      ((float*)out)[oi] = r;
    }
}

extern "C" void kernel_launch(void* const* d_in, const int* in_sizes, int n_in,
                              void* d_out, int out_size, void* d_ws, size_t ws_size,
                              hipStream_t stream)
{
    const void* g   = d_in[0];
    const void* h1w = d_in[3];
    const void* h1b = d_in[4];
    const void* h2w = d_in[5];
    const void* h2b = d_in[6];
    const void* rw  = d_in[7];
    const void* tw  = d_in[8];
    const void* a1w = d_in[9];
    const void* a1b = d_in[10];
    const void* a2w = d_in[11];
    const void* a2b = d_in[12];

    char* ws = (char*)d_ws;
    size_t off = 0;
    auto take = [&](size_t bytes) { size_t r = off; off = (off + bytes + 255) & ~(size_t)255; return r; };

    constexpr size_t N_GRID_CL = (size_t)NB*GN*GN*NC;           // bf16
    constexpr size_t N_WT1  = 9*NC*NH;                          // f32
    constexpr size_t N_B1   = NH;
    constexpr size_t N_W2T  = 9*5*CIP*32;                       // bf16
    constexpr size_t N_B2   = CIP;
    constexpr size_t N_WRT  = 9*5*80*32;                        // bf16
    constexpr size_t N_A1W  = NH*NA;
    constexpr size_t N_A1B  = NH;
    constexpr size_t N_A2W  = NA*NH;
    constexpr size_t N_A2B  = NA;
    constexpr size_t N_H    = (size_t)NB*GN*GN*CIP;             // bf16 (h1 / h2, padded)
    constexpr size_t N_RT   = (size_t)NB*NP*RTC;                // f32
    constexpr size_t N_Q    = (size_t)NB*NP*NA;                 // f32
    constexpr size_t N_STU  = (size_t)NB*NP*36;                 // u32 packed sT
    constexpr size_t N_REWB = (size_t)NB*NP;                    // f32

    size_t off_flag   = take(4);
    size_t off_gridcl = take(N_GRID_CL * 2);
    size_t off_wT1    = take(N_WT1 * 4);
    size_t off_b1     = take(N_B1 * 4);
    size_t off_w2t    = take(N_W2T * 2);
    size_t off_b2     = take(N_B2 * 4);
    size_t off_wrt    = take(N_WRT * 2);
    size_t off_wA1    = take(N_A1W * 4);
    size_t off_bA1    = take(N_A1B * 4);
    size_t off_wA2    = take(N_A2W * 4);
    size_t off_bA2    = take(N_A2B * 4);
    size_t off_q      = take(N_Q * 4);
    // region A: h1 (bf16, padded) first; later reused for rt (f32) after conv2 consumed h1
    size_t szA = (N_RT * 4 > N_H * 2) ? N_RT * 4 : N_H * 2;
    size_t off_A      = take(szA);
    // region B: h2 (bf16, padded); after convRT consumes h2, reused for sTu + rewb
    size_t szB = N_H * 2;
    size_t szB2 = ((N_STU * 4 + 255) & ~(size_t)255) + N_REWB * 4;
    if (szB2 > szB) szB = szB2;
    size_t off_B      = take(szB);

    int*      flag    = (int*)(ws + off_flag);
    uint16_t* grid_cl = (uint16_t*)(ws + off_gridcl);
    float*    wT1     = (float*)(ws + off_wT1);
    float*    bias1   = (float*)(ws + off_b1);
    uint16_t* w2t     = (uint16_t*)(ws + off_w2t);
    float*    bias2   = (float*)(ws + off_b2);
    uint16_t* wrt     = (uint16_t*)(ws + off_wrt);
    float*    wA1     = (float*)(ws + off_wA1);
    float*    bA1     = (float*)(ws + off_bA1);
    float*    wA2     = (float*)(ws + off_wA2);
    float*    bA2     = (float*)(ws + off_bA2);
    float*    qbuf    = (float*)(ws + off_q);
    uint16_t* h1      = (uint16_t*)(ws + off_A);
    float*    rt      = (float*)(ws + off_A);
    uint16_t* h2      = (uint16_t*)(ws + off_B);
    uint32_t* sTu     = (uint32_t*)(ws + off_B);
    float*    rewb    = (float*)(ws + off_B + ((N_STU * 4 + 255) & ~(size_t)255));

    // 0. dtype detection (bf16 vs f32 inputs)
    detect_kernel<<<1, 64, 0, stream>>>((const uint16_t*)h2w, flag);
    // 1. layout prep + dtype conversion
    {
        int total = (int)(N_GRID_CL + N_WT1 + N_B1 + N_W2T + N_B2 + N_WRT
                          + N_A1W + N_A1B + N_A2W + N_A2B);
        prep_kernel<<<(total + 255)/256, 256, 0, stream>>>(
            g, h1w, h1b, h2w, h2b, rw, tw, a1w, a1b, a2w, a2b, flag,
            grid_cl, wT1, bias1, w2t, bias2, wrt, wA1, bA1, wA2, bA2);
    }
    // 2. conv1: 2->150 VALU, out [b][49][49][160] bf16
    conv1_cl<<<NB*GN*13, 192, 0, stream>>>(grid_cl, wT1, bias1, h1);
    // 3. conv2: 150->150 MFMA implicit GEMM (co split in 2), out h2 padded bf16
    //    grid = b x rg(7) x xg(4) x cs(2), 128 thr
    conv_mfma<CIP, 80, 1, GN, true, true>
        <<<NB*7*4*2, 128, 0, stream>>>(h1, w2t, bias2, (void*)h2);
    // 4. reward+trans: 150->73 MFMA, pad 2, out 51x51 f32 (overwrites h1 region)
    //    grid = b x rg(7) x xg(4), 128 thr
    conv_mfma<80, 80, 2, HPN, false, false>
        <<<NB*7*4, 128, 0, stream>>>(h2, wrt, nullptr, (void*)rt);
    // 5. softmax + u16 pack (h2 dead -> overwritten by sTu/rewb)
    softmax_pack_kernel<<<(NB*NP + 255)/256, 256, 0, stream>>>(rt, sTu, rewb);
    // 6. value iteration (persistent, one block per batch, sT register-resident)
    vi_kernel<<<NB, 1024, 0, stream>>>(sTu, rewb, qbuf);
    // 7. head
    head_kernel<<<(NB*GN*GN + 255)/256, 256, 0, stream>>>(qbuf, wA1, bA1, wA2, bA2, flag,
                                                          d_out);
}

// Round 10
// 1264.962 us; speedup vs baseline: 1.1294x; 1.1294x over previous
//
#include <hip/hip_runtime.h>
#include <hip/hip_bf16.h>
#include <stdint.h>

// Problem constants
constexpr int NB   = 128;   // batch
constexpr int NC   = 2;     // grid channels
constexpr int NH   = 150;   // hidden
constexpr int NA   = 8;     // actions
constexpr int KIT  = 30;    // VI iterations
constexpr int GN   = 49;    // grid spatial
constexpr int HPN  = 51;    // padded spatial (49+2)
constexpr int NP   = HPN * HPN;  // 2601 positions
constexpr int RTC  = 73;    // 1 reward + 72 trans channels
constexpr int CIP  = 160;   // padded channel count (multiple of 32)

typedef short v8bf __attribute__((ext_vector_type(8)));
typedef float v4f  __attribute__((ext_vector_type(4)));

__device__ __forceinline__ float bf_lo(uint32_t u){ return __uint_as_float(u << 16); }
__device__ __forceinline__ float bf_hi(uint32_t u){ return __uint_as_float(u & 0xffff0000u); }

__device__ __forceinline__ uint16_t f2bf(float f) {
    uint32_t u = __float_as_uint(f);
    uint32_t lsb = (u >> 16) & 1u;
    u += 0x7fffu + lsb;
    return (uint16_t)(u >> 16);
}

// Load element i of a buffer whose dtype is bf16 (isbf=1) or f32 (isbf=0), as float.
__device__ __forceinline__ float ld_f(const void* p, size_t i, int isbf) {
    if (isbf) {
        uint32_t b = ((const uint16_t*)p)[i];
        return __uint_as_float(b << 16);
    }
    return ((const float*)p)[i];
}
__device__ __forceinline__ uint16_t ld_bf_bits(const void* p, size_t i, int isbf) {
    if (isbf) return ((const uint16_t*)p)[i];
    return f2bf(((const float*)p)[i]);
}

// ---------------- dtype sniffer ---------------------------------------------------------
__global__ void detect_kernel(const uint16_t* __restrict__ w, int* __restrict__ flag)
{
    int i = threadIdx.x;  // 0..63
    uint32_t bits = w[2 * i];
    float f = __uint_as_float(bits << 16);
    float a = fabsf(f);
    bool ok = (a >= 1e-10f && a <= 1e5f);
    unsigned long long m = __ballot(ok);
    if (i == 0) flag[0] = (__popcll(m) >= 48) ? 1 : 0;
}

// ---------------- prep: layout transforms -----------------------------------------------
// grid_cl [b][49][49][2] bf16 ; wT1 f32 [(k*2+ci)*150+co] ; bias1 f32[150]
// w2t bf16 [tap][kc5][160 co][32 ci]  (zero padded)  ; bias2 f32[160]
// wrt bf16 [tap][kc5][80 co][32 ci]   (co0 = reward, co1..72 = trans, zero padded)
__global__ void prep_kernel(const void* __restrict__ g,
                            const void* __restrict__ w1,
                            const void* __restrict__ b1,
                            const void* __restrict__ w2,
                            const void* __restrict__ b2,
                            const void* __restrict__ rw,
                            const void* __restrict__ tw,
                            const void* __restrict__ a1w,
                            const void* __restrict__ a1b,
                            const void* __restrict__ a2w,
                            const void* __restrict__ a2b,
                            const int* __restrict__ flag,
                            uint16_t* __restrict__ grid_cl,
                            float* __restrict__ wT1, float* __restrict__ bias1,
                            uint16_t* __restrict__ w2t, float* __restrict__ bias2,
                            uint16_t* __restrict__ wrt,
                            float* __restrict__ wA1, float* __restrict__ bA1,
                            float* __restrict__ wA2, float* __restrict__ bA2)
{
    constexpr int N_GRID = NB * GN * GN * NC;        // 614656
    constexpr int N_WT1  = 9 * NC * NH;              // 2700
    constexpr int N_B1   = NH;
    constexpr int N_W2T  = 9 * 5 * CIP * 32;         // 230400
    constexpr int N_B2   = CIP;
    constexpr int N_WRT  = 9 * 5 * 80 * 32;          // 115200
    constexpr int N_A1W  = NH * NA;
    constexpr int N_A1B  = NH;
    constexpr int N_A2W  = NA * NH;
    constexpr int N_A2B  = NA;

    int isbf = flag[0];
    int i = blockIdx.x * blockDim.x + threadIdx.x;
    if (i < N_GRID) {
        int c = i & 1; int s = (i >> 1) % (GN*GN); int b = i / (GN*GN*2);
        grid_cl[i] = ld_bf_bits(g, (size_t)(b*NC + c)*(GN*GN) + s, isbf);
        return;
    }
    i -= N_GRID;
    if (i < N_WT1) {
        int co = i % NH; int r = i / NH; int ci = r & 1; int k = r >> 1;
        wT1[i] = ld_f(w1, (size_t)co*(NC*9) + ci*9 + k, isbf);
        return;
    }
    i -= N_WT1;
    if (i < N_B1) { bias1[i] = ld_f(b1, i, isbf); return; }
    i -= N_B1;
    if (i < N_W2T) {
        int c  = i % 32;
        int co = (i / 32) % CIP;
        int kc = (i / (32*CIP)) % 5;
        int tap = i / (32*CIP*5);
        int ci = kc*32 + c;
        uint16_t v = 0;
        if (co < NH && ci < NH)
            v = f2bf(ld_f(w2, ((size_t)co*NH + ci)*9 + tap, isbf));
        w2t[i] = v;
        return;
    }
    i -= N_W2T;
    if (i < N_B2) { bias2[i] = (i < NH) ? ld_f(b2, i, isbf) : 0.f; return; }
    i -= N_B2;
    if (i < N_WRT) {
        int c  = i % 32;
        int co = (i / 32) % 80;
        int kc = (i / 2560) % 5;
        int tap = i / 12800;
        int ci = kc*32 + c;
        uint16_t v = 0;
        if (ci < NH) {
            if (co == 0)        v = f2bf(ld_f(rw, (size_t)ci*9 + tap, isbf));
            else if (co <= 72)  v = f2bf(ld_f(tw, ((size_t)(co-1)*NH + ci)*9 + tap, isbf));
        }
        wrt[i] = v;
        return;
    }
    i -= N_WRT;
    if (i < N_A1W) { wA1[i] = ld_f(a1w, i, isbf); return; }
    i -= N_A1W;
    if (i < N_A1B) { bA1[i] = ld_f(a1b, i, isbf); return; }
    i -= N_A1B;
    if (i < N_A2W) { wA2[i] = ld_f(a2w, i, isbf); return; }
    i -= N_A2W;
    if (i < N_A2B) { bA2[i] = ld_f(a2b, i, isbf); return; }
}

// ---------------- conv1: 2->150 VALU, writes 160-padded bf16 ----------------------------
__global__ __launch_bounds__(192)
void conv1_cl(const uint16_t* __restrict__ in,   // [b][49][49][2] bf16
              const float* __restrict__ wT,      // [(k*2+ci)*150+co]
              const float* __restrict__ bias,    // f32 [150]
              uint16_t* __restrict__ out)        // [b][49][49][160] bf16
{
    constexpr int H = GN, XG = 13;
    int bid = blockIdx.x;
    int xg = bid % XG;
    int y  = (bid / XG) % H;
    int b  = bid / (XG * H);
    int x0 = xg * 4;
    int co = threadIdx.x;

    if (co >= NH) {
        if (co < CIP) {
            #pragma unroll
            for (int xi = 0; xi < 4; ++xi) {
                int x = x0 + xi;
                if (x < H) out[((size_t)(b*H + y)*H + x)*CIP + co] = 0;
            }
        }
        return;
    }

    float bv = bias[co];
    float acc[4] = {bv, bv, bv, bv};

    for (int ky = 0; ky < 3; ++ky) {
        int yy = y + ky - 1;
        if (yy < 0 || yy >= H) continue;
        const uint16_t* rowp = in + (size_t)(b * H + yy) * H * NC;
        #pragma unroll
        for (int kx = 0; kx < 3; ++kx) {
            const float* wp = wT + ((ky*3 + kx) * NC) * NH + co;
            float w0 = wp[0];
            float w1 = wp[NH];
            #pragma unroll
            for (int xi = 0; xi < 4; ++xi) {
                int xx = x0 + xi + kx - 1;
                if (xx < 0 || xx >= H) continue;
                uint32_t u = *(const uint32_t*)(rowp + (size_t)xx * NC);
                acc[xi] += bf_lo(u)*w0 + bf_hi(u)*w1;
            }
        }
    }
    #pragma unroll
    for (int xi = 0; xi < 4; ++xi) {
        int x = x0 + xi;
        if (x < H) out[((size_t)(b*H + y)*H + x)*CIP + co] = f2bf(fmaxf(acc[xi], 0.f));
    }
}

// ---------------- MFMA implicit-GEMM 3x3 conv, v8 ---------------------------------------
// R7 structure (192 thr, 2 rows/wave, barrier-free per-lane B, ping-pong regs) with the
// halo split into two ci phases (kc 0..2 = 96 ci, then kc 3..4 = 64 ci) in a 30 KB LDS
// buffer -> 5 blocks/CU (15 waves/CU, 1.67x R7). 3 barriers per block total.
template<int CO_T, int CO_S, int PAD, int OH, bool RELU, bool OBF>
__global__ __launch_bounds__(192)
void conv_mfma(const uint16_t* __restrict__ in,   // [b][49][49][160] bf16
               const uint16_t* __restrict__ wt,   // [tap][kc][CO_T][32] bf16
               const float* __restrict__ bias,
               void* __restrict__ outv)
{
    constexpr int H = GN;
    constexpr int NSUB = CO_S / 16;        // 5
    constexpr int CS = CO_T / CO_S;        // 2 (conv2) or 1 (RT)
    constexpr int ASP = 104;               // per-cell LDS stride in shorts (96 ci + 8 pad)
    static_assert(NSUB * 16 == CO_S && CS * CO_S == CO_T, "");

    __shared__ __align__(16) uint16_t shA[8 * 18 * ASP];   // 29952 B

    int bid = blockIdx.x;
    int cs = 0;
    if (CS > 1) { cs = bid % CS; bid /= CS; }
    int xg = bid & 3;
    int rg = (bid >> 2) % 9;
    int b  = bid / 36;
    int y0 = rg * 6, x0 = xg * 16;
    int co0 = cs * CO_S;
    int t = threadIdx.x;
    int w = t >> 6, l = t & 63;
    int lo16 = l & 15, q4 = l >> 4;

    // ---- halo stage for a ci phase: 8 rows x 18 cols x (nkc*4) 16B chunks
    auto stageHalo = [&](int kcBase, int nkc) {
        int nch = nkc * 4;
        int total = 8 * 18 * nch;
        for (int q = t; q < total; q += 192) {
            int ci8 = q % nch;
            int c   = (q / nch) % 18;
            int r   = q / (nch * 18);
            int yy = y0 + r - PAD, xx = x0 + c - PAD;
            uint4 v = make_uint4(0u, 0u, 0u, 0u);
            if (yy >= 0 && yy < H && xx >= 0 && xx < H)
                v = *(const uint4*)(in + ((size_t)(b*H + yy)*H + xx)*CIP + kcBase*32 + ci8*8);
            *(uint4*)(&shA[(r*18 + c)*ASP + ci8*8]) = v;
        }
    };

    // ---- per-lane B base: fragment (sg,n) = wbase + sg*CO_T*32 + n*512
    const uint16_t* wbase = wt + (size_t)co0*32 + lo16*32 + q4*8;

    v4f acc[2][NSUB];
    #pragma unroll
    for (int si = 0; si < 2; ++si)
        #pragma unroll
        for (int n = 0; n < NSUB; ++n)
            acc[si][n] = (v4f){0.f, 0.f, 0.f, 0.f};

    auto loadB = [&](int sg, v8bf* bf) {
        const uint16_t* p = wbase + (size_t)sg * (CO_T*32);
        #pragma unroll
        for (int n = 0; n < NSUB; ++n)
            bf[n] = *(const v8bf*)(p + n*512);
    };
    auto loadA = [&](int sg, int kcBase, v8bf* af) {
        int tap = sg / 5, kc = sg % 5;
        int ky = tap / 3, kx = tap % 3;
        const uint16_t* base = &shA[((2*w + ky)*18 + lo16 + kx)*ASP + (kc - kcBase)*32 + q4*8];
        af[0] = *(const v8bf*)(base);
        af[1] = *(const v8bf*)(base + 18*ASP);
    };
    auto compute = [&](v8bf* af, v8bf* bf) {
        #pragma unroll
        for (int n = 0; n < NSUB; ++n) {
            acc[0][n] = __builtin_amdgcn_mfma_f32_16x16x32_bf16(af[0], bf[n], acc[0][n], 0, 0, 0);
            acc[1][n] = __builtin_amdgcn_mfma_f32_16x16x32_bf16(af[1], bf[n], acc[1][n], 0, 0, 0);
        }
    };

    // ---- one barrier-free phase: stages = (tap 0..8) x (kc kcBase..kcBase+nkc-1)
    auto phase = [&](int kcBase, int nkc) {
        int nst = 9 * nkc;
        auto sg = [&](int i){ int tap = i / nkc, kco = i % nkc; return tap*5 + kcBase + kco; };
        v8bf bf0[NSUB], bf1[NSUB], af0[2], af1[2];
        loadB(sg(0), bf0); loadA(sg(0), kcBase, af0);
        for (int i = 0; i < nst - 1; i += 2) {
            loadB(sg(i+1), bf1); loadA(sg(i+1), kcBase, af1);
            compute(af0, bf0);
            if (i + 2 < nst) { loadB(sg(i+2), bf0); loadA(sg(i+2), kcBase, af0); }
            compute(af1, bf1);
        }
        if (nst & 1) compute(af0, bf0);
    };

    stageHalo(0, 3);
    __syncthreads();
    phase(0, 3);            // 27 stages, kc 0..2
    __syncthreads();        // all waves done reading phase-0 halo
    stageHalo(3, 2);
    __syncthreads();
    phase(3, 2);            // 18 stages, kc 3..4

    // ---- epilogue: C/D layout: co = co0 + n*16 + (l&15), x = x0 + q4*4 + reg
    #pragma unroll
    for (int si = 0; si < 2; ++si) {
        int y = y0 + 2*w + si;
        if (y >= OH) continue;
        #pragma unroll
        for (int n = 0; n < NSUB; ++n) {
            int co = co0 + n*16 + lo16;
            float bv = bias ? bias[co] : 0.f;
            #pragma unroll
            for (int r = 0; r < 4; ++r) {
                int x = x0 + q4*4 + r;
                if (x >= OH) continue;
                float v = acc[si][n][r] + bv;
                if (RELU) v = fmaxf(v, 0.f);
                if (OBF) {
                    ((uint16_t*)outv)[((size_t)(b*OH + y)*OH + x)*CIP + co] = f2bf(v);
                } else {
                    if (co < RTC)
                        ((float*)outv)[((size_t)(b*OH + y)*OH + x)*RTC + co] = v;
                }
            }
        }
    }
}

// ---------------- softmax + u16 fixed-point pack ----------------------------------------
__global__ void softmax_pack_kernel(const float* __restrict__ rt,
                                    uint32_t* __restrict__ sTu,
                                    float* __restrict__ rewb)
{
    int idx = blockIdx.x * blockDim.x + threadIdx.x;
    constexpr int TOT = NB * NP;
    if (idx >= TOT) return;
    const float* tp = rt + (size_t)idx * RTC;
    rewb[idx] = tp[0];
    uint32_t words[36];
    #pragma unroll
    for (int a = 0; a < NA; ++a) {
        const float* s = tp + 1 + a * 9;
        float v[9];
        float m = -1e30f;
        #pragma unroll
        for (int k = 0; k < 9; ++k) { v[k] = s[k]; m = fmaxf(m, v[k]); }
        float sum = 0.f;
        #pragma unroll
        for (int k = 0; k < 9; ++k) { v[k] = expf(v[k] - m); sum += v[k]; }
        float sc = 65535.f / sum;
        #pragma unroll
        for (int k = 0; k < 9; ++k) {
            int gi = a * 9 + k;
            uint32_t u = (uint32_t)__float2uint_rn(v[k] * sc);
            if (gi & 1) words[gi >> 1] |= (u << 16);
            else        words[gi >> 1] = u;
        }
    }
    uint32_t* op = sTu + (size_t)idx * 36;
    #pragma unroll
    for (int j = 0; j < 9; ++j)
        *(uint4*)(op + 4*j) = make_uint4(words[4*j], words[4*j+1], words[4*j+2], words[4*j+3]);
}

// ---------------- VI inner: one action-pair (9 dwords = 18 u16 taps) --------------------
__device__ __forceinline__ void vi_pair(const uint32_t* d, const float* pat,
                                        float r, float& qE, float& qO)
{
    float qe = 0.f, qo = 0.f;
    qe = fmaf((float)(d[0] & 0xffffu), pat[0], qe);
    qe = fmaf((float)(d[0] >> 16),     pat[1], qe);
    qe = fmaf((float)(d[1] & 0xffffu), pat[2], qe);
    qe = fmaf((float)(d[1] >> 16),     pat[3], qe);
    qe = fmaf((float)(d[2] & 0xffffu), pat[4], qe);
    qe = fmaf((float)(d[2] >> 16),     pat[5], qe);
    qe = fmaf((float)(d[3] & 0xffffu), pat[6], qe);
    qe = fmaf((float)(d[3] >> 16),     pat[7], qe);
    qe = fmaf((float)(d[4] & 0xffffu), pat[8], qe);
    qo = fmaf((float)(d[4] >> 16),     pat[0], qo);
    qo = fmaf((float)(d[5] & 0xffffu), pat[1], qo);
    qo = fmaf((float)(d[5] >> 16),     pat[2], qo);
    qo = fmaf((float)(d[6] & 0xffffu), pat[3], qo);
    qo = fmaf((float)(d[6] >> 16),     pat[4], qo);
    qo = fmaf((float)(d[7] & 0xffffu), pat[5], qo);
    qo = fmaf((float)(d[7] >> 16),     pat[6], qo);
    qo = fmaf((float)(d[8] & 0xffffu), pat[7], qo);
    qo = fmaf((float)(d[8] >> 16),     pat[8], qo);
    constexpr float inv = 1.f / 65535.f;
    qE = fmaf(qe, inv, r);
    qO = fmaf(qo, inv, r);
}

// ---------------- persistent value iteration: sT register-resident ----------------------
__global__ __launch_bounds__(1024, 1)
void vi_kernel(const uint32_t* __restrict__ sTu, const float* __restrict__ rewb,
               float* __restrict__ qout)
{
    __shared__ float vb[2][53*53];
    __shared__ float rew[NP];
    int b = blockIdx.x, t = threadIdx.x;
    for (int i = t; i < 53*53; i += 1024) { vb[0][i] = 0.f; vb[1][i] = 0.f; }
    const uint32_t* sb = sTu + (size_t)b * NP * 36;
    for (int i = t; i < NP; i += 1024) rew[i] = rewb[(size_t)b * NP + i];

    int p0 = t, p1 = t + 1024, p2 = t + 2048;
    uint32_t s0[36], s1[36];
    {
        const uint4* a0 = (const uint4*)(sb + (size_t)p0 * 36);
        const uint4* a1 = (const uint4*)(sb + (size_t)p1 * 36);
        #pragma unroll
        for (int j = 0; j < 9; ++j) {
            uint4 v = a0[j];
            s0[4*j+0]=v.x; s0[4*j+1]=v.y; s0[4*j+2]=v.z; s0[4*j+3]=v.w;
            uint4 u = a1[j];
            s1[4*j+0]=u.x; s1[4*j+1]=u.y; s1[4*j+2]=u.z; s1[4*j+3]=u.w;
        }
    }
    __syncthreads();

    float* qb = qout + (size_t)b * NP * NA;
    int cur = 0;
    for (int it = 0; it < KIT; ++it) {
        bool last = (it == KIT - 1);
        const float* vc = vb[cur];
        float* vn = vb[cur ^ 1];
        {
            int y = p0 / HPN, x = p0 % HPN;
            float pat[9];
            #pragma unroll
            for (int dy = 0; dy < 3; ++dy)
                #pragma unroll
                for (int dx = 0; dx < 3; ++dx)
                    pat[dy*3+dx] = vc[(y+dy)*53 + x+dx];
            float r = rew[p0];
            float best = -3.4e38f;
            #pragma unroll
            for (int ap = 0; ap < 4; ++ap) {
                float qE, qO;
                vi_pair(s0 + ap*9, pat, r, qE, qO);
                best = fmaxf(best, fmaxf(qE, qO));
                if (last) {
                    qb[(size_t)p0*NA + 2*ap]     = qE;
                    qb[(size_t)p0*NA + 2*ap + 1] = qO;
                }
            }
            vn[(y+1)*53 + x+1] = best;
        }
        {
            int y = p1 / HPN, x = p1 % HPN;
            float pat[9];
            #pragma unroll
            for (int dy = 0; dy < 3; ++dy)
                #pragma unroll
                for (int dx = 0; dx < 3; ++dx)
                    pat[dy*3+dx] = vc[(y+dy)*53 + x+dx];
            float r = rew[p1];
            float best = -3.4e38f;
            #pragma unroll
            for (int ap = 0; ap < 4; ++ap) {
                float qE, qO;
                vi_pair(s1 + ap*9, pat, r, qE, qO);
                best = fmaxf(best, fmaxf(qE, qO));
                if (last) {
                    qb[(size_t)p1*NA + 2*ap]     = qE;
                    qb[(size_t)p1*NA + 2*ap + 1] = qO;
                }
            }
            vn[(y+1)*53 + x+1] = best;
        }
        if (t < NP - 2048) {
            int y = p2 / HPN, x = p2 % HPN;
            float pat[9];
            #pragma unroll
            for (int dy = 0; dy < 3; ++dy)
                #pragma unroll
                for (int dx = 0; dx < 3; ++dx)
                    pat[dy*3+dx] = vc[(y+dy)*53 + x+dx];
            float r = rew[p2];
            float best = -3.4e38f;
            const uint32_t* gp = sb + (size_t)p2 * 36;
            #pragma unroll
            for (int ap = 0; ap < 4; ++ap) {
                uint32_t d[9];
                #pragma unroll
                for (int j = 0; j < 9; ++j) d[j] = gp[ap*9 + j];
                float qE, qO;
                vi_pair(d, pat, r, qE, qO);
                best = fmaxf(best, fmaxf(qE, qO));
                if (last) {
                    qb[(size_t)p2*NA + 2*ap]     = qE;
                    qb[(size_t)p2*NA + 2*ap + 1] = qO;
                }
            }
            vn[(y+1)*53 + x+1] = best;
        }
        __syncthreads();
        cur ^= 1;
    }
}

// ---------------- fused MLP head: q(8) -> relu(150) -> logits(8) -------------------------
__global__ void head_kernel(const float* __restrict__ q,
                            const float* __restrict__ wA1,
                            const float* __restrict__ bA1,
                            const float* __restrict__ wA2,
                            const float* __restrict__ bA2,
                            const int* __restrict__ flag,
                            void* __restrict__ out)
{
    __shared__ float w1[NH*NA], sb1[NH], w2[NA*NH], sb2[NA];
    int t = threadIdx.x;
    for (int i = t; i < NH*NA; i += 256) w1[i] = wA1[i];
    for (int i = t; i < NH;    i += 256) sb1[i] = bA1[i];
    for (int i = t; i < NA*NH; i += 256) w2[i] = wA2[i];
    if (t < NA) sb2[t] = bA2[t];
    __syncthreads();

    int isbf = flag[0];
    int idx = blockIdx.x * 256 + t;
    constexpr int TOT = NB * GN * GN;
    if (idx >= TOT) return;
    int x = idx % GN, y = (idx / GN) % GN, b = idx / (GN*GN);
    const float* qp = q + ((size_t)(b*HPN + y)*HPN + x) * NA;
    float qv[NA];
    #pragma unroll
    for (int a = 0; a < NA; ++a) qv[a] = qp[a];
    float lg[NA];
    #pragma unroll
    for (int a = 0; a < NA; ++a) lg[a] = sb2[a];
    for (int c = 0; c < NH; ++c) {
        float m = sb1[c];
        #pragma unroll
        for (int a = 0; a < NA; ++a) m += qv[a] * w1[c*NA + a];
        m = fmaxf(m, 0.f);
        #pragma unroll
        for (int a = 0; a < NA; ++a) lg[a] += m * w2[a*NH + c];
    }
    #pragma unroll
    for (int a = 0; a < NA; ++a) {
        size_t oi = ((size_t)(b*NA + a)*GN + y)*GN + x;
        float r = lg[a];
        if (isbf) ((uint16_t*)out)[oi] = f2bf(r);
        else      ((float*)out)[oi] = r;
    }
}

extern "C" void kernel_launch(void* const* d_in, const int* in_sizes, int n_in,
                              void* d_out, int out_size, void* d_ws, size_t ws_size,
                              hipStream_t stream)
{
    const void* g   = d_in[0];
    const void* h1w = d_in[3];
    const void* h1b = d_in[4];
    const void* h2w = d_in[5];
    const void* h2b = d_in[6];
    const void* rw  = d_in[7];
    const void* tw  = d_in[8];
    const void* a1w = d_in[9];
    const void* a1b = d_in[10];
    const void* a2w = d_in[11];
    const void* a2b = d_in[12];

    char* ws = (char*)d_ws;
    size_t off = 0;
    auto take = [&](size_t bytes) { size_t r = off; off = (off + bytes + 255) & ~(size_t)255; return r; };

    constexpr size_t N_GRID_CL = (size_t)NB*GN*GN*NC;           // bf16
    constexpr size_t N_WT1  = 9*NC*NH;                          // f32
    constexpr size_t N_B1   = NH;
    constexpr size_t N_W2T  = 9*5*CIP*32;                       // bf16
    constexpr size_t N_B2   = CIP;
    constexpr size_t N_WRT  = 9*5*80*32;                        // bf16
    constexpr size_t N_A1W  = NH*NA;
    constexpr size_t N_A1B  = NH;
    constexpr size_t N_A2W  = NA*NH;
    constexpr size_t N_A2B  = NA;
    constexpr size_t N_H    = (size_t)NB*GN*GN*CIP;             // bf16 (h1 / h2, padded)
    constexpr size_t N_RT   = (size_t)NB*NP*RTC;                // f32
    constexpr size_t N_Q    = (size_t)NB*NP*NA;                 // f32
    constexpr size_t N_STU  = (size_t)NB*NP*36;                 // u32 packed sT
    constexpr size_t N_REWB = (size_t)NB*NP;                    // f32

    size_t off_flag   = take(4);
    size_t off_gridcl = take(N_GRID_CL * 2);
    size_t off_wT1    = take(N_WT1 * 4);
    size_t off_b1     = take(N_B1 * 4);
    size_t off_w2t    = take(N_W2T * 2);
    size_t off_b2     = take(N_B2 * 4);
    size_t off_wrt    = take(N_WRT * 2);
    size_t off_wA1    = take(N_A1W * 4);
    size_t off_bA1    = take(N_A1B * 4);
    size_t off_wA2    = take(N_A2W * 4);
    size_t off_bA2    = take(N_A2B * 4);
    size_t off_q      = take(N_Q * 4);
    // region A: h1 (bf16, padded) first; later reused for rt (f32) after conv2 consumed h1
    size_t szA = (N_RT * 4 > N_H * 2) ? N_RT * 4 : N_H * 2;
    size_t off_A      = take(szA);
    // region B: h2 (bf16, padded); after convRT consumes h2, reused for sTu + rewb
    size_t szB = N_H * 2;
    size_t szB2 = ((N_STU * 4 + 255) & ~(size_t)255) + N_REWB * 4;
    if (szB2 > szB) szB = szB2;
    size_t off_B      = take(szB);

    int*      flag    = (int*)(ws + off_flag);
    uint16_t* grid_cl = (uint16_t*)(ws + off_gridcl);
    float*    wT1     = (float*)(ws + off_wT1);
    float*    bias1   = (float*)(ws + off_b1);
    uint16_t* w2t     = (uint16_t*)(ws + off_w2t);
    float*    bias2   = (float*)(ws + off_b2);
    uint16_t* wrt     = (uint16_t*)(ws + off_wrt);
    float*    wA1     = (float*)(ws + off_wA1);
    float*    bA1     = (float*)(ws + off_bA1);
    float*    wA2     = (float*)(ws + off_wA2);
    float*    bA2     = (float*)(ws + off_bA2);
    float*    qbuf    = (float*)(ws + off_q);
    uint16_t* h1      = (uint16_t*)(ws + off_A);
    float*    rt      = (float*)(ws + off_A);
    uint16_t* h2      = (uint16_t*)(ws + off_B);
    uint32_t* sTu     = (uint32_t*)(ws + off_B);
    float*    rewb    = (float*)(ws + off_B + ((N_STU * 4 + 255) & ~(size_t)255));

    // 0. dtype detection (bf16 vs f32 inputs)
    detect_kernel<<<1, 64, 0, stream>>>((const uint16_t*)h2w, flag);
    // 1. layout prep + dtype conversion
    {
        int total = (int)(N_GRID_CL + N_WT1 + N_B1 + N_W2T + N_B2 + N_WRT
                          + N_A1W + N_A1B + N_A2W + N_A2B);
        prep_kernel<<<(total + 255)/256, 256, 0, stream>>>(
            g, h1w, h1b, h2w, h2b, rw, tw, a1w, a1b, a2w, a2b, flag,
            grid_cl, wT1, bias1, w2t, bias2, wrt, wA1, bA1, wA2, bA2);
    }
    // 2. conv1: 2->150 VALU, out [b][49][49][160] bf16
    conv1_cl<<<NB*GN*13, 192, 0, stream>>>(grid_cl, wT1, bias1, h1);
    // 3. conv2: 150->150 MFMA implicit GEMM (co split in 2), out h2 padded bf16
    conv_mfma<CIP, 80, 1, GN, true, true>
        <<<NB*36*2, 192, 0, stream>>>(h1, w2t, bias2, (void*)h2);
    // 4. reward+trans: 150->73 MFMA, pad 2, out 51x51 f32 (overwrites h1 region)
    conv_mfma<80, 80, 2, HPN, false, false>
        <<<NB*36, 192, 0, stream>>>(h2, wrt, nullptr, (void*)rt);
    // 5. softmax + u16 pack (h2 dead -> overwritten by sTu/rewb)
    softmax_pack_kernel<<<(NB*NP + 255)/256, 256, 0, stream>>>(rt, sTu, rewb);
    // 6. value iteration (persistent, one block per batch, sT register-resident)
    vi_kernel<<<NB, 1024, 0, stream>>>(sTu, rewb, qbuf);
    // 7. head
    head_kernel<<<(NB*GN*GN + 255)/256, 256, 0, stream>>>(qbuf, wA1, bA1, wA2, bA2, flag,
                                                          d_out);
}

// Round 11
// 1135.929 us; speedup vs baseline: 1.2577x; 1.1136x over previous
//
#include <hip/hip_runtime.h>
#include <hip/hip_bf16.h>
#include <stdint.h>

// Problem constants
constexpr int NB   = 128;   // batch
constexpr int NC   = 2;     // grid channels
constexpr int NH   = 150;   // hidden
constexpr int NA   = 8;     // actions
constexpr int KIT  = 30;    // VI iterations
constexpr int GN   = 49;    // grid spatial
constexpr int HPN  = 51;    // padded spatial (49+2)
constexpr int NP   = HPN * HPN;  // 2601 positions
constexpr int RTC  = 73;    // 1 reward + 72 trans channels
constexpr int CIP  = 160;   // padded channel count (multiple of 32)

typedef short v8bf __attribute__((ext_vector_type(8)));
typedef float v4f  __attribute__((ext_vector_type(4)));

__device__ __forceinline__ float bf_lo(uint32_t u){ return __uint_as_float(u << 16); }
__device__ __forceinline__ float bf_hi(uint32_t u){ return __uint_as_float(u & 0xffff0000u); }

__device__ __forceinline__ uint16_t f2bf(float f) {
    uint32_t u = __float_as_uint(f);
    uint32_t lsb = (u >> 16) & 1u;
    u += 0x7fffu + lsb;
    return (uint16_t)(u >> 16);
}

// Load element i of a buffer whose dtype is bf16 (isbf=1) or f32 (isbf=0), as float.
__device__ __forceinline__ float ld_f(const void* p, size_t i, int isbf) {
    if (isbf) {
        uint32_t b = ((const uint16_t*)p)[i];
        return __uint_as_float(b << 16);
    }
    return ((const float*)p)[i];
}
__device__ __forceinline__ uint16_t ld_bf_bits(const void* p, size_t i, int isbf) {
    if (isbf) return ((const uint16_t*)p)[i];
    return f2bf(((const float*)p)[i]);
}

// ---------------- dtype sniffer ---------------------------------------------------------
__global__ void detect_kernel(const uint16_t* __restrict__ w, int* __restrict__ flag)
{
    int i = threadIdx.x;  // 0..63
    uint32_t bits = w[2 * i];
    float f = __uint_as_float(bits << 16);
    float a = fabsf(f);
    bool ok = (a >= 1e-10f && a <= 1e5f);
    unsigned long long m = __ballot(ok);
    if (i == 0) flag[0] = (__popcll(m) >= 48) ? 1 : 0;
}

// ---------------- prep: layout transforms -----------------------------------------------
// grid_cl [b][49][49][2] bf16 ; wT1 f32 [(k*2+ci)*150+co] ; bias1 f32[150]
// w2t bf16 [tap][kc5][160 co][32 ci]  (zero padded)  ; bias2 f32[160]
// wrt bf16 [tap][kc5][80 co][32 ci]   (co0 = reward, co1..72 = trans, zero padded)
__global__ void prep_kernel(const void* __restrict__ g,
                            const void* __restrict__ w1,
                            const void* __restrict__ b1,
                            const void* __restrict__ w2,
                            const void* __restrict__ b2,
                            const void* __restrict__ rw,
                            const void* __restrict__ tw,
                            const void* __restrict__ a1w,
                            const void* __restrict__ a1b,
                            const void* __restrict__ a2w,
                            const void* __restrict__ a2b,
                            const int* __restrict__ flag,
                            uint16_t* __restrict__ grid_cl,
                            float* __restrict__ wT1, float* __restrict__ bias1,
                            uint16_t* __restrict__ w2t, float* __restrict__ bias2,
                            uint16_t* __restrict__ wrt,
                            float* __restrict__ wA1, float* __restrict__ bA1,
                            float* __restrict__ wA2, float* __restrict__ bA2)
{
    constexpr int N_GRID = NB * GN * GN * NC;        // 614656
    constexpr int N_WT1  = 9 * NC * NH;              // 2700
    constexpr int N_B1   = NH;
    constexpr int N_W2T  = 9 * 5 * CIP * 32;         // 230400
    constexpr int N_B2   = CIP;
    constexpr int N_WRT  = 9 * 5 * 80 * 32;          // 115200
    constexpr int N_A1W  = NH * NA;
    constexpr int N_A1B  = NH;
    constexpr int N_A2W  = NA * NH;
    constexpr int N_A2B  = NA;

    int isbf = flag[0];
    int i = blockIdx.x * blockDim.x + threadIdx.x;
    if (i < N_GRID) {
        int c = i & 1; int s = (i >> 1) % (GN*GN); int b = i / (GN*GN*2);
        grid_cl[i] = ld_bf_bits(g, (size_t)(b*NC + c)*(GN*GN) + s, isbf);
        return;
    }
    i -= N_GRID;
    if (i < N_WT1) {
        int co = i % NH; int r = i / NH; int ci = r & 1; int k = r >> 1;
        wT1[i] = ld_f(w1, (size_t)co*(NC*9) + ci*9 + k, isbf);
        return;
    }
    i -= N_WT1;
    if (i < N_B1) { bias1[i] = ld_f(b1, i, isbf); return; }
    i -= N_B1;
    if (i < N_W2T) {
        int c  = i % 32;
        int co = (i / 32) % CIP;
        int kc = (i / (32*CIP)) % 5;
        int tap = i / (32*CIP*5);
        int ci = kc*32 + c;
        uint16_t v = 0;
        if (co < NH && ci < NH)
            v = f2bf(ld_f(w2, ((size_t)co*NH + ci)*9 + tap, isbf));
        w2t[i] = v;
        return;
    }
    i -= N_W2T;
    if (i < N_B2) { bias2[i] = (i < NH) ? ld_f(b2, i, isbf) : 0.f; return; }
    i -= N_B2;
    if (i < N_WRT) {
        int c  = i % 32;
        int co = (i / 32) % 80;
        int kc = (i / 2560) % 5;
        int tap = i / 12800;
        int ci = kc*32 + c;
        uint16_t v = 0;
        if (ci < NH) {
            if (co == 0)        v = f2bf(ld_f(rw, (size_t)ci*9 + tap, isbf));
            else if (co <= 72)  v = f2bf(ld_f(tw, ((size_t)(co-1)*NH + ci)*9 + tap, isbf));
        }
        wrt[i] = v;
        return;
    }
    i -= N_WRT;
    if (i < N_A1W) { wA1[i] = ld_f(a1w, i, isbf); return; }
    i -= N_A1W;
    if (i < N_A1B) { bA1[i] = ld_f(a1b, i, isbf); return; }
    i -= N_A1B;
    if (i < N_A2W) { wA2[i] = ld_f(a2w, i, isbf); return; }
    i -= N_A2W;
    if (i < N_A2B) { bA2[i] = ld_f(a2b, i, isbf); return; }
}

// ---------------- conv1: 2->150 VALU, writes 160-padded bf16 ----------------------------
__global__ __launch_bounds__(192)
void conv1_cl(const uint16_t* __restrict__ in,   // [b][49][49][2] bf16
              const float* __restrict__ wT,      // [(k*2+ci)*150+co]
              const float* __restrict__ bias,    // f32 [150]
              uint16_t* __restrict__ out)        // [b][49][49][160] bf16
{
    constexpr int H = GN, XG = 13;
    int bid = blockIdx.x;
    int xg = bid % XG;
    int y  = (bid / XG) % H;
    int b  = bid / (XG * H);
    int x0 = xg * 4;
    int co = threadIdx.x;

    if (co >= NH) {
        if (co < CIP) {
            #pragma unroll
            for (int xi = 0; xi < 4; ++xi) {
                int x = x0 + xi;
                if (x < H) out[((size_t)(b*H + y)*H + x)*CIP + co] = 0;
            }
        }
        return;
    }

    float bv = bias[co];
    float acc[4] = {bv, bv, bv, bv};

    for (int ky = 0; ky < 3; ++ky) {
        int yy = y + ky - 1;
        if (yy < 0 || yy >= H) continue;
        const uint16_t* rowp = in + (size_t)(b * H + yy) * H * NC;
        #pragma unroll
        for (int kx = 0; kx < 3; ++kx) {
            const float* wp = wT + ((ky*3 + kx) * NC) * NH + co;
            float w0 = wp[0];
            float w1 = wp[NH];
            #pragma unroll
            for (int xi = 0; xi < 4; ++xi) {
                int xx = x0 + xi + kx - 1;
                if (xx < 0 || xx >= H) continue;
                uint32_t u = *(const uint32_t*)(rowp + (size_t)xx * NC);
                acc[xi] += bf_lo(u)*w0 + bf_hi(u)*w1;
            }
        }
    }
    #pragma unroll
    for (int xi = 0; xi < 4; ++xi) {
        int x = x0 + xi;
        if (x < H) out[((size_t)(b*H + y)*H + x)*CIP + co] = f2bf(fmaxf(acc[xi], 0.f));
    }
}

// ---------------- MFMA implicit-GEMM 3x3 conv, v9 ---------------------------------------
// R10's phase-split halo + R8's 4-rows-per-wave B amortization:
// block = 128 thr (2 waves), tile 8 rows x 16 cols x CO_S; halo in two ci phases
// (kc 0..2 then 3..4) in a 37.4 KB buffer -> 4 blocks/CU (2 waves/SIMD). Per stage per
// wave: 20 MFMA vs 5 per-lane global B loads (half the L2 B-traffic of R10). Barrier-free
// within phases; 3 barriers/block.
template<int CO_T, int CO_S, int PAD, int OH, bool RELU, bool OBF>
__global__ __launch_bounds__(128)
void conv_mfma(const uint16_t* __restrict__ in,   // [b][49][49][160] bf16
               const uint16_t* __restrict__ wt,   // [tap][kc][CO_T][32] bf16
               const float* __restrict__ bias,
               void* __restrict__ outv)
{
    constexpr int H = GN;
    constexpr int NSUB = CO_S / 16;        // 5
    constexpr int CS = CO_T / CO_S;        // 2 (conv2) or 1 (RT)
    constexpr int ASP = 104;               // per-cell LDS stride in shorts (96 ci + 8 pad)
    constexpr int RG = (OH + 7) / 8;       // 8-row tiles (7)
    static_assert(NSUB * 16 == CO_S && CS * CO_S == CO_T, "");

    __shared__ __align__(16) uint16_t shA[10 * 18 * ASP];   // 37440 B

    int bid = blockIdx.x;
    int cs = 0;
    if (CS > 1) { cs = bid % CS; bid /= CS; }
    int xg = bid & 3; bid >>= 2;
    int rg = bid % RG;
    int b  = bid / RG;
    int y0 = rg * 8, x0 = xg * 16;
    int co0 = cs * CO_S;
    int t = threadIdx.x;
    int w = t >> 6, l = t & 63;
    int lo16 = l & 15, q4 = l >> 4;

    // ---- halo stage for a ci phase: 10 rows x 18 cols x (nkc*4) 16B chunks
    auto stageHalo = [&](int kcBase, int nkc) {
        int nch = nkc * 4;
        int total = 10 * 18 * nch;
        for (int q = t; q < total; q += 128) {
            int ci8 = q % nch;
            int c   = (q / nch) % 18;
            int r   = q / (nch * 18);
            int yy = y0 + r - PAD, xx = x0 + c - PAD;
            uint4 v = make_uint4(0u, 0u, 0u, 0u);
            if (yy >= 0 && yy < H && xx >= 0 && xx < H)
                v = *(const uint4*)(in + ((size_t)(b*H + yy)*H + xx)*CIP + kcBase*32 + ci8*8);
            *(uint4*)(&shA[(r*18 + c)*ASP + ci8*8]) = v;
        }
    };

    // ---- per-lane B base: fragment (sg,n) = wbase + sg*CO_T*32 + n*512
    const uint16_t* wbase = wt + (size_t)co0*32 + lo16*32 + q4*8;

    v4f acc[4][NSUB];
    #pragma unroll
    for (int si = 0; si < 4; ++si)
        #pragma unroll
        for (int n = 0; n < NSUB; ++n)
            acc[si][n] = (v4f){0.f, 0.f, 0.f, 0.f};

    auto loadB = [&](int sg, v8bf* bf) {
        const uint16_t* p = wbase + (size_t)sg * (CO_T*32);
        #pragma unroll
        for (int n = 0; n < NSUB; ++n)
            bf[n] = *(const v8bf*)(p + n*512);
    };
    auto loadA = [&](int sg, int kcBase, v8bf* af) {
        int tap = sg / 5, kc = sg % 5;
        int ky = tap / 3, kx = tap % 3;
        const uint16_t* base = &shA[((4*w + ky)*18 + lo16 + kx)*ASP + (kc - kcBase)*32 + q4*8];
        #pragma unroll
        for (int si = 0; si < 4; ++si)
            af[si] = *(const v8bf*)(base + si*(18*ASP));
    };
    auto compute = [&](v8bf* af, v8bf* bf) {
        #pragma unroll
        for (int n = 0; n < NSUB; ++n) {
            #pragma unroll
            for (int si = 0; si < 4; ++si)
                acc[si][n] = __builtin_amdgcn_mfma_f32_16x16x32_bf16(af[si], bf[n], acc[si][n], 0, 0, 0);
        }
    };

    // ---- one barrier-free phase: stages = (tap 0..8) x (kc kcBase..kcBase+nkc-1)
    auto phase = [&](int kcBase, int nkc) {
        int nst = 9 * nkc;
        auto sg = [&](int i){ int tap = i / nkc, kco = i % nkc; return tap*5 + kcBase + kco; };
        v8bf bf0[NSUB], bf1[NSUB], af0[4], af1[4];
        loadB(sg(0), bf0); loadA(sg(0), kcBase, af0);
        for (int i = 0; i < nst - 1; i += 2) {
            loadB(sg(i+1), bf1); loadA(sg(i+1), kcBase, af1);
            compute(af0, bf0);
            if (i + 2 < nst) { loadB(sg(i+2), bf0); loadA(sg(i+2), kcBase, af0); }
            compute(af1, bf1);
        }
        if (nst & 1) compute(af0, bf0);
    };

    stageHalo(0, 3);
    __syncthreads();
    phase(0, 3);            // 27 stages, kc 0..2
    __syncthreads();        // all waves done reading phase-0 halo
    stageHalo(3, 2);
    __syncthreads();
    phase(3, 2);            // 18 stages, kc 3..4

    // ---- epilogue: C/D layout: co = co0 + n*16 + (l&15), x = x0 + q4*4 + reg
    #pragma unroll
    for (int si = 0; si < 4; ++si) {
        int y = y0 + 4*w + si;
        if (y >= OH) continue;
        #pragma unroll
        for (int n = 0; n < NSUB; ++n) {
            int co = co0 + n*16 + lo16;
            float bv = bias ? bias[co] : 0.f;
            #pragma unroll
            for (int r = 0; r < 4; ++r) {
                int x = x0 + q4*4 + r;
                if (x >= OH) continue;
                float v = acc[si][n][r] + bv;
                if (RELU) v = fmaxf(v, 0.f);
                if (OBF) {
                    ((uint16_t*)outv)[((size_t)(b*OH + y)*OH + x)*CIP + co] = f2bf(v);
                } else {
                    if (co < RTC)
                        ((float*)outv)[((size_t)(b*OH + y)*OH + x)*RTC + co] = v;
                }
            }
        }
    }
}

// ---------------- softmax + u16 fixed-point pack ----------------------------------------
__global__ void softmax_pack_kernel(const float* __restrict__ rt,
                                    uint32_t* __restrict__ sTu,
                                    float* __restrict__ rewb)
{
    int idx = blockIdx.x * blockDim.x + threadIdx.x;
    constexpr int TOT = NB * NP;
    if (idx >= TOT) return;
    const float* tp = rt + (size_t)idx * RTC;
    rewb[idx] = tp[0];
    uint32_t words[36];
    #pragma unroll
    for (int a = 0; a < NA; ++a) {
        const float* s = tp + 1 + a * 9;
        float v[9];
        float m = -1e30f;
        #pragma unroll
        for (int k = 0; k < 9; ++k) { v[k] = s[k]; m = fmaxf(m, v[k]); }
        float sum = 0.f;
        #pragma unroll
        for (int k = 0; k < 9; ++k) { v[k] = expf(v[k] - m); sum += v[k]; }
        float sc = 65535.f / sum;
        #pragma unroll
        for (int k = 0; k < 9; ++k) {
            int gi = a * 9 + k;
            uint32_t u = (uint32_t)__float2uint_rn(v[k] * sc);
            if (gi & 1) words[gi >> 1] |= (u << 16);
            else        words[gi >> 1] = u;
        }
    }
    uint32_t* op = sTu + (size_t)idx * 36;
    #pragma unroll
    for (int j = 0; j < 9; ++j)
        *(uint4*)(op + 4*j) = make_uint4(words[4*j], words[4*j+1], words[4*j+2], words[4*j+3]);
}

// ---------------- VI inner: one action-pair (9 dwords = 18 u16 taps) --------------------
__device__ __forceinline__ void vi_pair(const uint32_t* d, const float* pat,
                                        float r, float& qE, float& qO)
{
    float qe = 0.f, qo = 0.f;
    qe = fmaf((float)(d[0] & 0xffffu), pat[0], qe);
    qe = fmaf((float)(d[0] >> 16),     pat[1], qe);
    qe = fmaf((float)(d[1] & 0xffffu), pat[2], qe);
    qe = fmaf((float)(d[1] >> 16),     pat[3], qe);
    qe = fmaf((float)(d[2] & 0xffffu), pat[4], qe);
    qe = fmaf((float)(d[2] >> 16),     pat[5], qe);
    qe = fmaf((float)(d[3] & 0xffffu), pat[6], qe);
    qe = fmaf((float)(d[3] >> 16),     pat[7], qe);
    qe = fmaf((float)(d[4] & 0xffffu), pat[8], qe);
    qo = fmaf((float)(d[4] >> 16),     pat[0], qo);
    qo = fmaf((float)(d[5] & 0xffffu), pat[1], qo);
    qo = fmaf((float)(d[5] >> 16),     pat[2], qo);
    qo = fmaf((float)(d[6] & 0xffffu), pat[3], qo);
    qo = fmaf((float)(d[6] >> 16),     pat[4], qo);
    qo = fmaf((float)(d[7] & 0xffffu), pat[5], qo);
    qo = fmaf((float)(d[7] >> 16),     pat[6], qo);
    qo = fmaf((float)(d[8] & 0xffffu), pat[7], qo);
    qo = fmaf((float)(d[8] >> 16),     pat[8], qo);
    constexpr float inv = 1.f / 65535.f;
    qE = fmaf(qe, inv, r);
    qO = fmaf(qo, inv, r);
}

// ---------------- persistent value iteration: sT register-resident ----------------------
__global__ __launch_bounds__(1024, 1)
void vi_kernel(const uint32_t* __restrict__ sTu, const float* __restrict__ rewb,
               float* __restrict__ qout)
{
    __shared__ float vb[2][53*53];
    __shared__ float rew[NP];
    int b = blockIdx.x, t = threadIdx.x;
    for (int i = t; i < 53*53; i += 1024) { vb[0][i] = 0.f; vb[1][i] = 0.f; }
    const uint32_t* sb = sTu + (size_t)b * NP * 36;
    for (int i = t; i < NP; i += 1024) rew[i] = rewb[(size_t)b * NP + i];

    int p0 = t, p1 = t + 1024, p2 = t + 2048;
    uint32_t s0[36], s1[36];
    {
        const uint4* a0 = (const uint4*)(sb + (size_t)p0 * 36);
        const uint4* a1 = (const uint4*)(sb + (size_t)p1 * 36);
        #pragma unroll
        for (int j = 0; j < 9; ++j) {
            uint4 v = a0[j];
            s0[4*j+0]=v.x; s0[4*j+1]=v.y; s0[4*j+2]=v.z; s0[4*j+3]=v.w;
            uint4 u = a1[j];
            s1[4*j+0]=u.x; s1[4*j+1]=u.y; s1[4*j+2]=u.z; s1[4*j+3]=u.w;
        }
    }
    __syncthreads();

    float* qb = qout + (size_t)b * NP * NA;
    int cur = 0;
    for (int it = 0; it < KIT; ++it) {
        bool last = (it == KIT - 1);
        const float* vc = vb[cur];
        float* vn = vb[cur ^ 1];
        {
            int y = p0 / HPN, x = p0 % HPN;
            float pat[9];
            #pragma unroll
            for (int dy = 0; dy < 3; ++dy)
                #pragma unroll
                for (int dx = 0; dx < 3; ++dx)
                    pat[dy*3+dx] = vc[(y+dy)*53 + x+dx];
            float r = rew[p0];
            float best = -3.4e38f;
            #pragma unroll
            for (int ap = 0; ap < 4; ++ap) {
                float qE, qO;
                vi_pair(s0 + ap*9, pat, r, qE, qO);
                best = fmaxf(best, fmaxf(qE, qO));
                if (last) {
                    qb[(size_t)p0*NA + 2*ap]     = qE;
                    qb[(size_t)p0*NA + 2*ap + 1] = qO;
                }
            }
            vn[(y+1)*53 + x+1] = best;
        }
        {
            int y = p1 / HPN, x = p1 % HPN;
            float pat[9];
            #pragma unroll
            for (int dy = 0; dy < 3; ++dy)
                #pragma unroll
                for (int dx = 0; dx < 3; ++dx)
                    pat[dy*3+dx] = vc[(y+dy)*53 + x+dx];
            float r = rew[p1];
            float best = -3.4e38f;
            #pragma unroll
            for (int ap = 0; ap < 4; ++ap) {
                float qE, qO;
                vi_pair(s1 + ap*9, pat, r, qE, qO);
                best = fmaxf(best, fmaxf(qE, qO));
                if (last) {
                    qb[(size_t)p1*NA + 2*ap]     = qE;
                    qb[(size_t)p1*NA + 2*ap + 1] = qO;
                }
            }
            vn[(y+1)*53 + x+1] = best;
        }
        if (t < NP - 2048) {
            int y = p2 / HPN, x = p2 % HPN;
            float pat[9];
            #pragma unroll
            for (int dy = 0; dy < 3; ++dy)
                #pragma unroll
                for (int dx = 0; dx < 3; ++dx)
                    pat[dy*3+dx] = vc[(y+dy)*53 + x+dx];
            float r = rew[p2];
            float best = -3.4e38f;
            const uint32_t* gp = sb + (size_t)p2 * 36;
            #pragma unroll
            for (int ap = 0; ap < 4; ++ap) {
                uint32_t d[9];
                #pragma unroll
                for (int j = 0; j < 9; ++j) d[j] = gp[ap*9 + j];
                float qE, qO;
                vi_pair(d, pat, r, qE, qO);
                best = fmaxf(best, fmaxf(qE, qO));
                if (last) {
                    qb[(size_t)p2*NA + 2*ap]     = qE;
                    qb[(size_t)p2*NA + 2*ap + 1] = qO;
                }
            }
            vn[(y+1)*53 + x+1] = best;
        }
        __syncthreads();
        cur ^= 1;
    }
}

// ---------------- fused MLP head: q(8) -> relu(150) -> logits(8) -------------------------
__global__ void head_kernel(const float* __restrict__ q,
                            const float* __restrict__ wA1,
                            const float* __restrict__ bA1,
                            const float* __restrict__ wA2,
                            const float* __restrict__ bA2,
                            const int* __restrict__ flag,
                            void* __restrict__ out)
{
    __shared__ float w1[NH*NA], sb1[NH], w2[NA*NH], sb2[NA];
    int t = threadIdx.x;
    for (int i = t; i < NH*NA; i += 256) w1[i] = wA1[i];
    for (int i = t; i < NH;    i += 256) sb1[i] = bA1[i];
    for (int i = t; i < NA*NH; i += 256) w2[i] = wA2[i];
    if (t < NA) sb2[t] = bA2[t];
    __syncthreads();

    int isbf = flag[0];
    int idx = blockIdx.x * 256 + t;
    constexpr int TOT = NB * GN * GN;
    if (idx >= TOT) return;
    int x = idx % GN, y = (idx / GN) % GN, b = idx / (GN*GN);
    const float* qp = q + ((size_t)(b*HPN + y)*HPN + x) * NA;
    float qv[NA];
    #pragma unroll
    for (int a = 0; a < NA; ++a) qv[a] = qp[a];
    float lg[NA];
    #pragma unroll
    for (int a = 0; a < NA; ++a) lg[a] = sb2[a];
    for (int c = 0; c < NH; ++c) {
        float m = sb1[c];
        #pragma unroll
        for (int a = 0; a < NA; ++a) m += qv[a] * w1[c*NA + a];
        m = fmaxf(m, 0.f);
        #pragma unroll
        for (int a = 0; a < NA; ++a) lg[a] += m * w2[a*NH + c];
    }
    #pragma unroll
    for (int a = 0; a < NA; ++a) {
        size_t oi = ((size_t)(b*NA + a)*GN + y)*GN + x;
        float r = lg[a];
        if (isbf) ((uint16_t*)out)[oi] = f2bf(r);
        else      ((float*)out)[oi] = r;
    }
}

extern "C" void kernel_launch(void* const* d_in, const int* in_sizes, int n_in,
                              void* d_out, int out_size, void* d_ws, size_t ws_size,
                              hipStream_t stream)
{
    const void* g   = d_in[0];
    const void* h1w = d_in[3];
    const void* h1b = d_in[4];
    const void* h2w = d_in[5];
    const void* h2b = d_in[6];
    const void* rw  = d_in[7];
    const void* tw  = d_in[8];
    const void* a1w = d_in[9];
    const void* a1b = d_in[10];
    const void* a2w = d_in[11];
    const void* a2b = d_in[12];

    char* ws = (char*)d_ws;
    size_t off = 0;
    auto take = [&](size_t bytes) { size_t r = off; off = (off + bytes + 255) & ~(size_t)255; return r; };

    constexpr size_t N_GRID_CL = (size_t)NB*GN*GN*NC;           // bf16
    constexpr size_t N_WT1  = 9*NC*NH;                          // f32
    constexpr size_t N_B1   = NH;
    constexpr size_t N_W2T  = 9*5*CIP*32;                       // bf16
    constexpr size_t N_B2   = CIP;
    constexpr size_t N_WRT  = 9*5*80*32;                        // bf16
    constexpr size_t N_A1W  = NH*NA;
    constexpr size_t N_A1B  = NH;
    constexpr size_t N_A2W  = NA*NH;
    constexpr size_t N_A2B  = NA;
    constexpr size_t N_H    = (size_t)NB*GN*GN*CIP;             // bf16 (h1 / h2, padded)
    constexpr size_t N_RT   = (size_t)NB*NP*RTC;                // f32
    constexpr size_t N_Q    = (size_t)NB*NP*NA;                 // f32
    constexpr size_t N_STU  = (size_t)NB*NP*36;                 // u32 packed sT
    constexpr size_t N_REWB = (size_t)NB*NP;                    // f32

    size_t off_flag   = take(4);
    size_t off_gridcl = take(N_GRID_CL * 2);
    size_t off_wT1    = take(N_WT1 * 4);
    size_t off_b1     = take(N_B1 * 4);
    size_t off_w2t    = take(N_W2T * 2);
    size_t off_b2     = take(N_B2 * 4);
    size_t off_wrt    = take(N_WRT * 2);
    size_t off_wA1    = take(N_A1W * 4);
    size_t off_bA1    = take(N_A1B * 4);
    size_t off_wA2    = take(N_A2W * 4);
    size_t off_bA2    = take(N_A2B * 4);
    size_t off_q      = take(N_Q * 4);
    // region A: h1 (bf16, padded) first; later reused for rt (f32) after conv2 consumed h1
    size_t szA = (N_RT * 4 > N_H * 2) ? N_RT * 4 : N_H * 2;
    size_t off_A      = take(szA);
    // region B: h2 (bf16, padded); after convRT consumes h2, reused for sTu + rewb
    size_t szB = N_H * 2;
    size_t szB2 = ((N_STU * 4 + 255) & ~(size_t)255) + N_REWB * 4;
    if (szB2 > szB) szB = szB2;
    size_t off_B      = take(szB);

    int*      flag    = (int*)(ws + off_flag);
    uint16_t* grid_cl = (uint16_t*)(ws + off_gridcl);
    float*    wT1     = (float*)(ws + off_wT1);
    float*    bias1   = (float*)(ws + off_b1);
    uint16_t* w2t     = (uint16_t*)(ws + off_w2t);
    float*    bias2   = (float*)(ws + off_b2);
    uint16_t* wrt     = (uint16_t*)(ws + off_wrt);
    float*    wA1     = (float*)(ws + off_wA1);
    float*    bA1     = (float*)(ws + off_bA1);
    float*    wA2     = (float*)(ws + off_wA2);
    float*    bA2     = (float*)(ws + off_bA2);
    float*    qbuf    = (float*)(ws + off_q);
    uint16_t* h1      = (uint16_t*)(ws + off_A);
    float*    rt      = (float*)(ws + off_A);
    uint16_t* h2      = (uint16_t*)(ws + off_B);
    uint32_t* sTu     = (uint32_t*)(ws + off_B);
    float*    rewb    = (float*)(ws + off_B + ((N_STU * 4 + 255) & ~(size_t)255));

    // 0. dtype detection (bf16 vs f32 inputs)
    detect_kernel<<<1, 64, 0, stream>>>((const uint16_t*)h2w, flag);
    // 1. layout prep + dtype conversion
    {
        int total = (int)(N_GRID_CL + N_WT1 + N_B1 + N_W2T + N_B2 + N_WRT
                          + N_A1W + N_A1B + N_A2W + N_A2B);
        prep_kernel<<<(total + 255)/256, 256, 0, stream>>>(
            g, h1w, h1b, h2w, h2b, rw, tw, a1w, a1b, a2w, a2b, flag,
            grid_cl, wT1, bias1, w2t, bias2, wrt, wA1, bA1, wA2, bA2);
    }
    // 2. conv1: 2->150 VALU, out [b][49][49][160] bf16
    conv1_cl<<<NB*GN*13, 192, 0, stream>>>(grid_cl, wT1, bias1, h1);
    // 3. conv2: 150->150 MFMA implicit GEMM (co split in 2), out h2 padded bf16
    //    grid = b x rg(7) x xg(4) x cs(2), 128 thr
    conv_mfma<CIP, 80, 1, GN, true, true>
        <<<NB*7*4*2, 128, 0, stream>>>(h1, w2t, bias2, (void*)h2);
    // 4. reward+trans: 150->73 MFMA, pad 2, out 51x51 f32 (overwrites h1 region)
    //    grid = b x rg(7) x xg(4), 128 thr
    conv_mfma<80, 80, 2, HPN, false, false>
        <<<NB*7*4, 128, 0, stream>>>(h2, wrt, nullptr, (void*)rt);
    // 5. softmax + u16 pack (h2 dead -> overwritten by sTu/rewb)
    softmax_pack_kernel<<<(NB*NP + 255)/256, 256, 0, stream>>>(rt, sTu, rewb);
    // 6. value iteration (persistent, one block per batch, sT register-resident)
    vi_kernel<<<NB, 1024, 0, stream>>>(sTu, rewb, qbuf);
    // 7. head
    head_kernel<<<(NB*GN*GN + 255)/256, 256, 0, stream>>>(qbuf, wA1, bA1, wA2, bA2, flag,
                                                          d_out);
}